// Round 5
// baseline (743.968 us; speedup 1.0000x reference)
//
#include <hip/hip_runtime.h>
#include <math.h>

#define N_NODES 131072
#define N_EDGES 2097152
#define DIM     64
#define BSUB    4096
#define NREL    3
#define NBASES  2
#define NXCD    8

typedef unsigned short u16;
typedef __attribute__((ext_vector_type(8))) short bf16x8;   // MFMA A/B frag (4 VGPRs)
typedef __attribute__((ext_vector_type(4))) float f32x4;    // MFMA C/D frag

__device__ __forceinline__ float bf2f(u16 x) {
    return __uint_as_float(((unsigned)x) << 16);
}
__device__ __forceinline__ u16 f2bf(float f) {
    unsigned u = __float_as_uint(f);
    unsigned r = (u + 0x7FFFu + ((u >> 16) & 1u)) >> 16;   // RNE
    return (u16)r;
}
__device__ __forceinline__ float4 bf4_to_f4(ushort4 u) {
    return make_float4(bf2f(u.x), bf2f(u.y), bf2f(u.z), bf2f(u.w));
}
__device__ __forceinline__ ushort4 f4_to_bf4(float4 v) {
    ushort4 o; o.x = f2bf(v.x); o.y = f2bf(v.y); o.z = f2bf(v.z); o.w = f2bf(v.w);
    return o;
}

// physical XCD id of the executing wave (wave-uniform SGPR). HW-verified on
// gfx950 (learn_hip m09): returns 0..7.
__device__ __forceinline__ int xcc_id() {
    int x;
    asm volatile("s_getreg_b32 %0, hwreg(HW_REG_XCC_ID)" : "=s"(x));
    return x & (NXCD - 1);
}

// ---------------- init: zero per-XCD counters + mark centers ----------------
// grid covers NXCD*N_NODES ints of cnt2; first N_NODES lanes also set mark.
__global__ void initmark_kernel(int* __restrict__ cnt2, int* __restrict__ mark) {
    int i = blockIdx.x * 256 + threadIdx.x;
    cnt2[i] = 0;
    if (i < N_NODES) mark[i] = (i < BSUB) ? 1 : 0;
}

// fused histogram + frontier mark + rank capture: one pass over (src, dst).
// R16: per-XCD counter slices + WORKGROUP-scope atomics. R2-R4 established
// that device-scope returning atomics are capped at ~24 G/s chip-wide
// (contention-independent: padding R14 -11%, 4x ILP R15 -6%) — they round-trip
// to the memory-side coherence point because per-XCD L2s aren't coherent.
// Workgroup-scope fetch_add on a slice touched only by this XCD executes in
// the local L2 (atomics bypass L1; all CUs of an XCD share the L2), giving
// XCD-local atomicity at L2 speed. rank packs (xcd << 24) | local_rank.
__global__ void histmark_kernel(const int* __restrict__ src, const int* __restrict__ dst,
                                int* __restrict__ cnt2, int* __restrict__ mark,
                                int* __restrict__ rank) {
    int x = xcc_id();
    int* cx = cnt2 + (size_t)x * N_NODES;
    int xt = x << 24;
    int e0 = (blockIdx.x * 256 + threadIdx.x) * 4;
    if (e0 >= N_EDGES) return;
    int4 d4 = *(const int4*)(dst + e0);
    int r0 = __hip_atomic_fetch_add(&cx[d4.x], 1, __ATOMIC_RELAXED, __HIP_MEMORY_SCOPE_WORKGROUP);
    int r1 = __hip_atomic_fetch_add(&cx[d4.y], 1, __ATOMIC_RELAXED, __HIP_MEMORY_SCOPE_WORKGROUP);
    int r2 = __hip_atomic_fetch_add(&cx[d4.z], 1, __ATOMIC_RELAXED, __HIP_MEMORY_SCOPE_WORKGROUP);
    int r3 = __hip_atomic_fetch_add(&cx[d4.w], 1, __ATOMIC_RELAXED, __HIP_MEMORY_SCOPE_WORKGROUP);
    // frontier marks (taken ~3% of edges; benign race: all write 1)
    if (d4.x < BSUB) mark[src[e0 + 0]] = 1;
    if (d4.y < BSUB) mark[src[e0 + 1]] = 1;
    if (d4.z < BSUB) mark[src[e0 + 2]] = 1;
    if (d4.w < BSUB) mark[src[e0 + 3]] = 1;
    *(int4*)(rank + e0) = make_int4(xt | r0, xt | r1, xt | r2, xt | r3);
}

// per-node exclusive prefix over the 8 XCD slices (in place); node total -> tot
__global__ void combine_kernel(int* __restrict__ cnt2, int* __restrict__ tot) {
    int n = blockIdx.x * 256 + threadIdx.x;
    int run = 0;
#pragma unroll
    for (int x = 0; x < NXCD; x++) {
        size_t i = (size_t)x * N_NODES + n;
        int v = cnt2[i];
        cnt2[i] = run;
        run += v;
    }
    tot[n] = run;
}

// fold offs[n] into every XCD slice base: cnt2[x][n] += offs[n]
__global__ void addoffs_kernel(int* __restrict__ cnt2, const int* __restrict__ offs) {
    int i = blockIdx.x * 256 + threadIdx.x;    // NXCD*N_NODES threads
    cnt2[i] += offs[i & (N_NODES - 1)];
}

// block-level exclusive scan of 256 ints (strided input); block total -> bsum
__global__ void scan1_kernel(const int* __restrict__ cnt, int stride,
                             int* __restrict__ scanned, int* __restrict__ bsum) {
    __shared__ int s[256];
    int tid = threadIdx.x;
    int i = blockIdx.x * 256 + tid;
    int v = cnt[(size_t)i * stride];
    s[tid] = v;
    __syncthreads();
    int val = v;
    for (int off = 1; off < 256; off <<= 1) {
        int tmp = (tid >= off) ? s[tid - off] : 0;
        __syncthreads();
        val += tmp;
        s[tid] = val;
        __syncthreads();
    }
    scanned[i] = val - v;                 // exclusive
    if (tid == 255) bsum[blockIdx.x] = val;
}

// exclusive scan of 512 block sums, in place
__global__ void scan2_kernel(int* __restrict__ bsum) {
    __shared__ int s[512];
    int tid = threadIdx.x;
    int v = bsum[tid];
    s[tid] = v;
    __syncthreads();
    int val = v;
    for (int off = 1; off < 512; off <<= 1) {
        int tmp = (tid >= off) ? s[tid - off] : 0;
        __syncthreads();
        val += tmp;
        s[tid] = val;
        __syncthreads();
    }
    bsum[tid] = val - v;
}

__global__ void scan3_kernel(int* __restrict__ offs, const int* __restrict__ bsum) {
    int i = blockIdx.x * 256 + threadIdx.x;
    offs[i] = offs[i] + bsum[blockIdx.x];
    if (i == 0) offs[N_NODES] = N_EDGES;
}

// compact marked nodes -> list[], write count to nld
__global__ void listfill_kernel(const int* __restrict__ mark, const int* __restrict__ mpref,
                                const int* __restrict__ mbsum, int* __restrict__ list,
                                int* __restrict__ nld) {
    int i = blockIdx.x * 256 + threadIdx.x;
    int pos = mpref[i] + mbsum[blockIdx.x];
    if (mark[i]) list[pos] = i;
    if (i == N_NODES - 1) *nld = pos + mark[i];
}

// single-pass scatter into CSR order; plain 16B stores, NO atomic.
// p = cnt2[xcd][d] + local_rank  (cnt2 holds offs[d] + per-XCD base after
// combine+addoffs). 4 edges/thread (R15).
// (R8-proven config kept: 16B payload, normal store. NT store (R11), 8B
// payload (R10), two-pass binning (R7), XCD range-filter (R12) all WORSE.)
__global__ void fill_kernel(const int* __restrict__ src, const int* __restrict__ dst,
                            const int* __restrict__ et, const float* __restrict__ m1,
                            const float* __restrict__ m2, const int* __restrict__ rank,
                            const int* __restrict__ cnt2, int4* __restrict__ csr) {
    int e0 = (blockIdx.x * 256 + threadIdx.x) * 4;
    if (e0 >= N_EDGES) return;
    int4  d4 = *(const int4*)(dst + e0);
    int4  s4 = *(const int4*)(src + e0);
    int4  t4 = *(const int4*)(et + e0);
    float4 a4 = *(const float4*)(m1 + e0);
    float4 b4 = *(const float4*)(m2 + e0);
    int4  r4 = *(const int4*)(rank + e0);
    int p0 = cnt2[((size_t)(r4.x >> 24) << 17) + d4.x] + (r4.x & 0xFFFFFF);
    int p1 = cnt2[((size_t)(r4.y >> 24) << 17) + d4.y] + (r4.y & 0xFFFFFF);
    int p2 = cnt2[((size_t)(r4.z >> 24) << 17) + d4.z] + (r4.z & 0xFFFFFF);
    int p3 = cnt2[((size_t)(r4.w >> 24) << 17) + d4.w] + (r4.w & 0xFFFFFF);
    int4 v0, v1, v2, v3;
    v0.x = s4.x | (t4.x << 20); v0.y = __float_as_int(a4.x); v0.z = __float_as_int(b4.x); v0.w = 0;
    v1.x = s4.y | (t4.y << 20); v1.y = __float_as_int(a4.y); v1.z = __float_as_int(b4.y); v1.w = 0;
    v2.x = s4.z | (t4.z << 20); v2.y = __float_as_int(a4.z); v2.z = __float_as_int(b4.z); v2.w = 0;
    v3.x = s4.w | (t4.w << 20); v3.y = __float_as_int(a4.w); v3.z = __float_as_int(b4.w); v3.w = 0;
    csr[p0] = v0;
    csr[p1] = v1;
    csr[p2] = v2;
    csr[p3] = v3;
}

// ---------------- x -> bf16 convert ----------------
__global__ void cvt_kernel(const float4* __restrict__ x, ushort4* __restrict__ hb, int n4) {
    int i = blockIdx.x * 256 + threadIdx.x;
    if (i < n4) hb[i] = f4_to_bf4(x[i]);
}

// ---------------- weight packing into MFMA B-fragment layout ----------------
// Wc[192][64]: rows 0..63 = V_b0, 64..127 = V_b1, 128..191 = W_self.
// wfrag[conv][nt(4)][kidx(6)][lane(64)][j(8)]; n = nt*16+(lane&15),
// k = kidx*32+(lane>>4)*8+j.
__global__ void wpack_kernel(const float* __restrict__ lV, const float* __restrict__ lW,
                             const float* __restrict__ gV, const float* __restrict__ gW,
                             u16* __restrict__ wfrag) {
    int idx = blockIdx.x * 256 + threadIdx.x;   // 6*4*6*64 = 9216
    if (idx >= 6 * 4 * 6 * 64) return;
    int lane = idx & 63;
    int kidx = (idx >> 6) % 6;
    int nt   = (idx >> 6) / 6 % 4;
    int c    = idx / (64 * 6 * 4);      // conv 0..5
    int layer = c >> 1;
    bool isglobal = c & 1;
    const float* V = isglobal ? gV : lV;
    const float* W = isglobal ? gW : lW;
    int n = nt * 16 + (lane & 15);
    int kbase = kidx * 32 + (lane >> 4) * 8;
    u16 vals[8];
#pragma unroll
    for (int j = 0; j < 8; j++) {
        int r = kbase + j;      // 0..191
        float val;
        if (r < NBASES * DIM) {
            int b = r >> 6, d = r & 63;
            val = V[((layer * NBASES + b) * DIM + d) * DIM + n];
        } else {
            int d = r - NBASES * DIM;
            val = W[(layer * DIM + d) * DIM + n];
        }
        vals[j] = f2bf(val);
    }
    ushort4* o = (ushort4*)(wfrag + (size_t)idx * 8);
    o[0] = make_ushort4(vals[0], vals[1], vals[2], vals[3]);
    o[1] = make_ushort4(vals[4], vals[5], vals[6], vals[7]);
}

// ---------------- edge aggregation (wave per dst node, basis-space, bf16 h) ------
// h: bf16 [N,64]. t: bf16 [N,128] (u_b0 | u_b1; self-loop folded into gemm).
// Quarter-wave gathers: lanes q*16..+15 fetch edge j+4s+q's 128B row.
// which: 0 -> m1 (csr.y), 1 -> m2 (csr.z).
// list != nullptr: process list[idx] for idx < *nld (layer-2 local pruning).
__global__ __launch_bounds__(256) void agg_kernel(
    const ushort4* __restrict__ hb, const int* __restrict__ offs,
    const int4* __restrict__ csr, const float* __restrict__ Cc,
    int which, ushort4* __restrict__ t, int nNodes,
    const int* __restrict__ list, const int* __restrict__ nld) {
    int lane = threadIdx.x & 63;
    int idx = (blockIdx.x << 2) + (threadIdx.x >> 6);
    int n;
    if (list) {
        if (idx >= *nld) return;
        n = list[idx];
    } else {
        if (idx >= nNodes) return;
        n = idx;
    }
    int q  = lane >> 4;     // quarter 0..3
    int ql = lane & 15;     // lane within quarter
    float Ca0 = Cc[0], Cb0 = Cc[1], Ca1 = Cc[2], Cb1 = Cc[3], Ca2 = Cc[4], Cb2 = Cc[5];
    int beg = offs[n], end = offs[n + 1];
    float4 a0 = make_float4(0.f, 0.f, 0.f, 0.f);
    float4 a1 = make_float4(0.f, 0.f, 0.f, 0.f);
    for (int base = beg; base < end; base += 64) {
        int cnt = min(64, end - base);
        int p = 0; float m = 0.f;
        if (lane < cnt) {
            int4 meta = csr[base + lane];
            p = meta.x;
            m = __int_as_float(which ? meta.z : meta.y);
        }
        for (int j = 0; j < cnt; j += 32) {
            int pe[8]; float me[8]; ushort4 r[8];
#pragma unroll
            for (int s = 0; s < 8; s++) {
                int jj = j + (s << 2) + q;
                int ii = jj < cnt ? jj : 0;
                pe[s] = __shfl(p, ii, 64);
                float mm = __shfl(m, ii, 64);
                me[s] = jj < cnt ? mm : 0.f;
            }
#pragma unroll
            for (int s = 0; s < 8; s++)
                r[s] = hb[((pe[s] & 0xFFFFF) << 4) + ql];
#pragma unroll
            for (int s = 0; s < 8; s++) {
                float4 v = bf4_to_f4(r[s]);
                int et = pe[s] >> 20;
                float ca = et == 0 ? Ca0 : (et == 1 ? Ca1 : Ca2);
                float cb = et == 0 ? Cb0 : (et == 1 ? Cb1 : Cb2);
                float c0 = me[s] * ca, c1 = me[s] * cb;
                a0.x = fmaf(c0, v.x, a0.x); a0.y = fmaf(c0, v.y, a0.y);
                a0.z = fmaf(c0, v.z, a0.z); a0.w = fmaf(c0, v.w, a0.w);
                a1.x = fmaf(c1, v.x, a1.x); a1.y = fmaf(c1, v.y, a1.y);
                a1.z = fmaf(c1, v.z, a1.z); a1.w = fmaf(c1, v.w, a1.w);
            }
        }
    }
#pragma unroll
    for (int off = 16; off < 64; off <<= 1) {
        a0.x += __shfl_xor(a0.x, off, 64); a0.y += __shfl_xor(a0.y, off, 64);
        a0.z += __shfl_xor(a0.z, off, 64); a0.w += __shfl_xor(a0.w, off, 64);
        a1.x += __shfl_xor(a1.x, off, 64); a1.y += __shfl_xor(a1.y, off, 64);
        a1.z += __shfl_xor(a1.z, off, 64); a1.w += __shfl_xor(a1.w, off, 64);
    }
    ushort4 outv = f4_to_bf4(q == 0 ? a0 : a1);
    if (q < 2)
        t[(size_t)n * 32 + (q << 4) + ql] = outv;
}

// ---------------- MFMA GEMM: [rows,128(t)|64(h self)] @ wfrag[192,64] -----------
// 4 waves/block; wave owns 16 row-slots x 64 cols; K = 6 x mfma_f32_16x16x32_bf16
// (kidx 0..3 A from t, kidx 4..5 A from h). list: indirect rows (layer-2 local).
__global__ __launch_bounds__(256) void gemm_kernel(
    const u16* __restrict__ t, const u16* __restrict__ h,
    const u16* __restrict__ wfrag, const float* __restrict__ bias,
    u16* __restrict__ hout, float* __restrict__ subg, int subg_off, int act,
    const int* __restrict__ list, const int* __restrict__ nld) {
    int tid = threadIdx.x;
    int wave = tid >> 6, lane = tid & 63;
    int l16 = lane & 15, quad = lane >> 4;
    int nL = list ? *nld : 0;
    if (list && blockIdx.x * 64 >= nL) return;
    int slot0 = blockIdx.x * 64 + wave * 16;
    int myslot = slot0 + l16;
    int rowA = list ? list[min(myslot, nL - 1)] : myslot;
    const u16* trow = t + (size_t)rowA * 128;
    const u16* hrow = h + (size_t)rowA * 64;
    f32x4 acc0 = {0.f, 0.f, 0.f, 0.f};
    f32x4 acc1 = {0.f, 0.f, 0.f, 0.f};
    f32x4 acc2 = {0.f, 0.f, 0.f, 0.f};
    f32x4 acc3 = {0.f, 0.f, 0.f, 0.f};
#pragma unroll
    for (int kidx = 0; kidx < 6; kidx++) {
        bf16x8 a = (kidx < 4)
            ? *(const bf16x8*)(trow + kidx * 32 + quad * 8)
            : *(const bf16x8*)(hrow + (kidx - 4) * 32 + quad * 8);
        bf16x8 b0 = *(const bf16x8*)(wfrag + ((size_t)(0 * 6 + kidx) * 64 + lane) * 8);
        bf16x8 b1 = *(const bf16x8*)(wfrag + ((size_t)(1 * 6 + kidx) * 64 + lane) * 8);
        bf16x8 b2 = *(const bf16x8*)(wfrag + ((size_t)(2 * 6 + kidx) * 64 + lane) * 8);
        bf16x8 b3 = *(const bf16x8*)(wfrag + ((size_t)(3 * 6 + kidx) * 64 + lane) * 8);
        acc0 = __builtin_amdgcn_mfma_f32_16x16x32_bf16(a, b0, acc0, 0, 0, 0);
        acc1 = __builtin_amdgcn_mfma_f32_16x16x32_bf16(a, b1, acc1, 0, 0, 0);
        acc2 = __builtin_amdgcn_mfma_f32_16x16x32_bf16(a, b2, acc2, 0, 0, 0);
        acc3 = __builtin_amdgcn_mfma_f32_16x16x32_bf16(a, b3, acc3, 0, 0, 0);
    }
    float accs[4][4] = {
        {acc0[0], acc0[1], acc0[2], acc0[3]},
        {acc1[0], acc1[1], acc1[2], acc1[3]},
        {acc2[0], acc2[1], acc2[2], acc2[3]},
        {acc3[0], acc3[1], acc3[2], acc3[3]},
    };
#pragma unroll
    for (int nt = 0; nt < 4; nt++) {
        int col = nt * 16 + l16;
        float bcol = bias[col];
#pragma unroll
        for (int r = 0; r < 4; r++) {
            int cslot = slot0 + quad * 4 + r;
            if (list && cslot >= nL) continue;
            int row = list ? __shfl(rowA, quad * 4 + r, 64) : cslot;
            float xv = accs[nt][r] + bcol;
            float v = act ? (xv > 0.f ? xv : 0.01f * xv)
                          : (xv > 0.f ? xv : expm1f(xv));
            hout[(size_t)row * 64 + col] = f2bf(v);
            if (subg && row < BSUB)
                subg[(size_t)row * 192 + subg_off + col] = v;
        }
    }
}

// ---------------- MLP head: [4096,192] -> relu 128 -> sigmoid 1 ----------------
__global__ __launch_bounds__(256) void head_kernel(
    const float* __restrict__ subg, const float* __restrict__ w1,
    const float* __restrict__ b1, const float* __restrict__ w2,
    const float* __restrict__ b2, float* __restrict__ out) {
    __shared__ float srow[4][192];
    int lane = threadIdx.x & 63, wid = threadIdx.x >> 6;
    int row = blockIdx.x * 4 + wid;
    const float* sr = subg + (size_t)row * 192;
    srow[wid][lane] = sr[lane];
    srow[wid][64 + lane] = sr[64 + lane];
    srow[wid][128 + lane] = sr[128 + lane];
    __syncthreads();
    float acc1 = b1[lane], acc2 = b1[64 + lane];
    const float* w1a = w1 + lane * 192;
    const float* w1b = w1 + (64 + lane) * 192;
    for (int k = 0; k < 192; k++) {
        float s = srow[wid][k];
        acc1 = fmaf(s, w1a[k], acc1);
        acc2 = fmaf(s, w1b[k], acc2);
    }
    acc1 = fmaxf(acc1, 0.f);
    acc2 = fmaxf(acc2, 0.f);
    float part = acc1 * w2[lane] + acc2 * w2[64 + lane];
    for (int off = 32; off; off >>= 1) part += __shfl_down(part, off, 64);
    if (lane == 0) out[row] = 1.f / (1.f + expf(-(part + b2[0])));
}

extern "C" void kernel_launch(void* const* d_in, const int* in_sizes, int n_in,
                              void* d_out, int out_size, void* d_ws, size_t ws_size,
                              hipStream_t stream) {
    const float* x     = (const float*)d_in[0];
    const int*   src   = (const int*)d_in[1];
    const int*   dst   = (const int*)d_in[2];
    const int*   etype = (const int*)d_in[3];
    const float* mask  = (const float*)d_in[4];
    const float* mask2 = (const float*)d_in[5];
    const float* lV = (const float*)d_in[6];
    const float* lC = (const float*)d_in[7];
    const float* lW = (const float*)d_in[8];
    const float* lB = (const float*)d_in[9];
    const float* gV = (const float*)d_in[10];
    const float* gC = (const float*)d_in[11];
    const float* gW = (const float*)d_in[12];
    const float* gB = (const float*)d_in[13];
    const float* w1 = (const float*)d_in[14];
    const float* b1 = (const float*)d_in[15];
    const float* w2 = (const float*)d_in[16];
    const float* b2 = (const float*)d_in[17];
    float* out = (float*)d_out;

    // workspace carve-up
    char* ws = (char*)d_ws;
    size_t off = 0;
    auto alloc = [&](size_t bytes) {
        void* p = ws + off;
        off += (bytes + 255) & ~(size_t)255;
        return p;
    };
    ushort4* h    = (ushort4*)alloc((size_t)N_NODES * 64 * 2);     // bf16 [N,64]
    ushort4* t    = (ushort4*)alloc((size_t)N_NODES * 128 * 2);    // bf16 [N,128]
    int4*  csr    = (int4*)alloc((size_t)N_EDGES * 16);
    int*   rank   = (int*)alloc((size_t)N_EDGES * 4);
    int*   offs   = (int*)alloc((size_t)(N_NODES + 1) * 4);
    int*   cnt2   = (int*)alloc((size_t)NXCD * N_NODES * 4);       // per-XCD slices
    int*   tot    = (int*)alloc((size_t)N_NODES * 4);
    int*   bsum   = (int*)alloc(512 * 4);
    int*   mark   = (int*)alloc((size_t)N_NODES * 4);
    int*   mpref  = (int*)alloc((size_t)N_NODES * 4);
    int*   mbsum  = (int*)alloc(512 * 4);
    int*   list   = (int*)alloc((size_t)N_NODES * 4);
    int*   nld    = (int*)alloc(256);
    u16*   wfrag  = (u16*)alloc((size_t)6 * 4 * 6 * 64 * 8 * 2);
    float* subg   = (float*)alloc((size_t)BSUB * 192 * 4);

    // ---- graph preprocessing ----
    initmark_kernel<<<NXCD * N_NODES / 256, 256, 0, stream>>>(cnt2, mark);
    histmark_kernel<<<N_EDGES / 1024, 256, 0, stream>>>(src, dst, cnt2, mark, rank);
    combine_kernel<<<N_NODES / 256, 256, 0, stream>>>(cnt2, tot);
    scan1_kernel<<<N_NODES / 256, 256, 0, stream>>>(tot, 1, offs, bsum);
    scan2_kernel<<<1, 512, 0, stream>>>(bsum);
    scan3_kernel<<<N_NODES / 256, 256, 0, stream>>>(offs, bsum);
    addoffs_kernel<<<NXCD * N_NODES / 256, 256, 0, stream>>>(cnt2, offs);
    fill_kernel<<<N_EDGES / 1024, 256, 0, stream>>>(src, dst, etype, mask, mask2,
                                                    rank, cnt2, csr);
    // frontier compaction for layer-2 local conv
    scan1_kernel<<<N_NODES / 256, 256, 0, stream>>>(mark, 1, mpref, mbsum);
    scan2_kernel<<<1, 512, 0, stream>>>(mbsum);
    listfill_kernel<<<N_NODES / 256, 256, 0, stream>>>(mark, mpref, mbsum, list, nld);
    wpack_kernel<<<(6 * 4 * 6 * 64 + 255) / 256, 256, 0, stream>>>(lV, lW, gV, gW, wfrag);
    cvt_kernel<<<(N_NODES * 64 / 4) / 256, 256, 0, stream>>>((const float4*)x, h,
                                                             N_NODES * 64 / 4);

    const int convfrag = 4 * 6 * 64 * 8;   // u16 elements per conv
    for (int layer = 0; layer < 3; layer++) {
        // local conv (mask, elu); layer 2: frontier-pruned
        const int* ll  = (layer == 2) ? list : nullptr;
        agg_kernel<<<N_NODES / 4, 256, 0, stream>>>(h, offs, csr,
            lC + layer * NREL * NBASES, 0, t, N_NODES, ll, nld);
        gemm_kernel<<<N_NODES / 64, 256, 0, stream>>>(
            (const u16*)t, (const u16*)h,
            wfrag + (size_t)(layer * 2 + 0) * convfrag, lB + layer * 64,
            (u16*)h, nullptr, 0, 0, ll, nld);
        // global conv (mask2, leaky_relu); layer 2: only BSUB rows
        int nG = (layer == 2) ? BSUB : N_NODES;
        agg_kernel<<<(nG + 3) / 4, 256, 0, stream>>>(h, offs, csr,
            gC + layer * NREL * NBASES, 1, t, nG, nullptr, nld);
        gemm_kernel<<<nG / 64, 256, 0, stream>>>(
            (const u16*)t, (const u16*)h,
            wfrag + (size_t)(layer * 2 + 1) * convfrag, gB + layer * 64,
            (u16*)h, subg, layer * 64, 1, nullptr, nld);
    }
    head_kernel<<<BSUB / 4, 256, 0, stream>>>(subg, w1, b1, w2, b2, out);
}

// Round 6
// 676.488 us; speedup vs baseline: 1.0998x; 1.0998x over previous
//
#include <hip/hip_runtime.h>
#include <math.h>

#define N_NODES 131072
#define N_EDGES 2097152
#define DIM     64
#define BSUB    4096
#define NREL    3
#define NBASES  2
#define NCB     256     // coarse buckets (dst >> 9)
#define CBSZ    8192    // edges per chist/cscatter block (256 blocks exactly)

typedef unsigned short u16;
typedef __attribute__((ext_vector_type(8))) short bf16x8;   // MFMA A/B frag (4 VGPRs)
typedef __attribute__((ext_vector_type(4))) float f32x4;    // MFMA C/D frag

__device__ __forceinline__ float bf2f(u16 x) {
    return __uint_as_float(((unsigned)x) << 16);
}
__device__ __forceinline__ u16 f2bf(float f) {
    unsigned u = __float_as_uint(f);
    unsigned r = (u + 0x7FFFu + ((u >> 16) & 1u)) >> 16;   // RNE
    return (u16)r;
}
__device__ __forceinline__ float4 bf4_to_f4(ushort4 u) {
    return make_float4(bf2f(u.x), bf2f(u.y), bf2f(u.z), bf2f(u.w));
}
__device__ __forceinline__ ushort4 f4_to_bf4(float4 v) {
    ushort4 o; o.x = f2bf(v.x); o.y = f2bf(v.y); o.z = f2bf(v.z); o.w = f2bf(v.w);
    return o;
}

// ================= R17: MSD bucket sort replaces atomic CSR build ==============
// R2-R5 established: global returning atomics are capped ~24 G/s chip-wide,
// invariant to line padding (R14), per-wave ILP (R15), and atomic scope (R16)
// — they execute memory-side (32 B/atomic WRITE traffic signature). So the
// 2M-edge rank build can never beat ~85 µs with atomics. This sort uses only
// LDS atomics per edge + 65K global atomics per pass (negligible).

// ---------------- init: mark centers + zero coarse histogram ----------------
__global__ void initmark_kernel(int* __restrict__ mark, int* __restrict__ chist) {
    int i = blockIdx.x * 256 + threadIdx.x;
    if (i < N_NODES) mark[i] = (i < BSUB) ? 1 : 0;
    if (i < NCB) chist[i] = 0;
}

// ---------------- pass A: coarse histogram (dst >> 9) ----------------
__global__ __launch_bounds__(256) void chist_kernel(const int* __restrict__ dst,
                                                    int* __restrict__ chist) {
    __shared__ int lh[NCB];
    int tid = threadIdx.x;
    lh[tid] = 0;
    __syncthreads();
    int base = blockIdx.x * CBSZ + tid;
#pragma unroll
    for (int j = 0; j < CBSZ / 256; j++)
        atomicAdd(&lh[dst[base + j * 256] >> 9], 1);
    __syncthreads();
    atomicAdd(&chist[tid], lh[tid]);     // non-returning, 256/block
}

// ---------------- coarse scan: chist -> cbase (excl) + ccur copy ----------------
__global__ void cscan_kernel(const int* __restrict__ chist, int* __restrict__ cbase,
                             int* __restrict__ ccur, int* __restrict__ offs) {
    __shared__ int s[NCB];
    int tid = threadIdx.x;
    int v = chist[tid];
    s[tid] = v;
    __syncthreads();
    int val = v;
    for (int off = 1; off < NCB; off <<= 1) {
        int tmp = (tid >= off) ? s[tid - off] : 0;
        __syncthreads();
        val += tmp;
        s[tid] = val;
        __syncthreads();
    }
    cbase[tid] = val - v;
    ccur[tid] = val - v;
    if (tid == 0) offs[N_NODES] = N_EDGES;
}

// ---------------- pass B: coarse scatter (full payload) + frontier mark --------
// Each block: LDS-hist its 8192 edges, claim per-bin runs (256 returning
// global atomics/block = 65K total), scatter {src|et, m1, m2, dst} into tmp.
// Runs avg 32 edges = 512 B -> full-line writes.
__global__ __launch_bounds__(256) void cscatter_kernel(
    const int* __restrict__ src, const int* __restrict__ dst,
    const int* __restrict__ et, const float* __restrict__ m1,
    const float* __restrict__ m2, int* __restrict__ ccur,
    int4* __restrict__ tmp, int* __restrict__ mark) {
    __shared__ int lh[NCB];
    __shared__ int lbase[NCB];
    int tid = threadIdx.x;
    lh[tid] = 0;
    __syncthreads();
    int e0 = blockIdx.x * CBSZ;
#pragma unroll
    for (int j = 0; j < CBSZ / 256; j++)
        atomicAdd(&lh[dst[e0 + tid + j * 256] >> 9], 1);
    __syncthreads();
    int c = lh[tid];
    lbase[tid] = c ? atomicAdd(&ccur[tid], c) : 0;
    lh[tid] = 0;                 // reuse as local cursor
    __syncthreads();
#pragma unroll
    for (int j = 0; j < CBSZ / 256; j++) {
        int e = e0 + tid + j * 256;
        int d = dst[e];
        int s = src[e];
        int b = d >> 9;
        int r = atomicAdd(&lh[b], 1);            // LDS returning
        int4 v;
        v.x = s | (et[e] << 20);
        v.y = __float_as_int(m1[e]);
        v.z = __float_as_int(m2[e]);
        v.w = d;
        tmp[lbase[b] + r] = v;
        if (d < BSUB) mark[s] = 1;               // benign race: all write 1
    }
}

// ---------------- pass C: fine scatter within coarse bucket + offs write -------
// One WG per bucket (512 nodes, ~8192 edges, 128 KB csr region -> XCD-L2-local).
// LDS 512-bin hist + scan -> offs[] directly; then scatter csr by LDS ranks.
__global__ __launch_bounds__(256) void fscatter_kernel(
    const int4* __restrict__ tmp, const int* __restrict__ cbase,
    const int* __restrict__ chist, int* __restrict__ offs,
    int4* __restrict__ csr) {
    __shared__ int lh[512];
    __shared__ int lpre[512];
    __shared__ int s2[256];
    int b = blockIdx.x;
    int tid = threadIdx.x;
    int base = cbase[b], cnt = chist[b];
    lh[tid] = 0; lh[tid + 256] = 0;
    __syncthreads();
    for (int i = tid; i < cnt; i += 256)
        atomicAdd(&lh[tmp[base + i].w & 511], 1);
    __syncthreads();
    // exclusive scan of 512 bins (pair + 256-scan + expand)
    int a0 = lh[2 * tid], a1 = lh[2 * tid + 1];
    s2[tid] = a0 + a1;
    __syncthreads();
    int val = s2[tid];
    for (int off = 1; off < 256; off <<= 1) {
        int t = (tid >= off) ? s2[tid - off] : 0;
        __syncthreads();
        val += t;
        s2[tid] = val;
        __syncthreads();
    }
    int ex = val - (a0 + a1);
    lpre[2 * tid] = ex;
    lpre[2 * tid + 1] = ex + a0;
    // offs for this bucket's 512 nodes
    offs[b * 512 + 2 * tid]     = base + ex;
    offs[b * 512 + 2 * tid + 1] = base + ex + a0;
    lh[tid] = 0; lh[tid + 256] = 0;    // reuse as cursors
    __syncthreads();
    for (int i = tid; i < cnt; i += 256) {
        int4 v = tmp[base + i];
        int k = v.w & 511;
        int r = atomicAdd(&lh[k], 1);            // LDS returning
        csr[base + lpre[k] + r] = v;             // .w carries dst (agg ignores)
    }
}

// block-level exclusive scan of 256 ints; block total -> bsum (mark compaction)
__global__ void scan1_kernel(const int* __restrict__ cnt, int* __restrict__ scanned,
                             int* __restrict__ bsum) {
    __shared__ int s[256];
    int tid = threadIdx.x;
    int i = blockIdx.x * 256 + tid;
    int v = cnt[i];
    s[tid] = v;
    __syncthreads();
    int val = v;
    for (int off = 1; off < 256; off <<= 1) {
        int tmp = (tid >= off) ? s[tid - off] : 0;
        __syncthreads();
        val += tmp;
        s[tid] = val;
        __syncthreads();
    }
    scanned[i] = val - v;                 // exclusive
    if (tid == 255) bsum[blockIdx.x] = val;
}

// exclusive scan of 512 block sums, in place
__global__ void scan2_kernel(int* __restrict__ bsum) {
    __shared__ int s[512];
    int tid = threadIdx.x;
    int v = bsum[tid];
    s[tid] = v;
    __syncthreads();
    int val = v;
    for (int off = 1; off < 512; off <<= 1) {
        int tmp = (tid >= off) ? s[tid - off] : 0;
        __syncthreads();
        val += tmp;
        s[tid] = val;
        __syncthreads();
    }
    bsum[tid] = val - v;
}

// compact marked nodes -> list[], write count to nld
__global__ void listfill_kernel(const int* __restrict__ mark, const int* __restrict__ mpref,
                                const int* __restrict__ mbsum, int* __restrict__ list,
                                int* __restrict__ nld) {
    int i = blockIdx.x * 256 + threadIdx.x;
    int pos = mpref[i] + mbsum[blockIdx.x];
    if (mark[i]) list[pos] = i;
    if (i == N_NODES - 1) *nld = pos + mark[i];
}

// ---------------- x -> bf16 convert ----------------
__global__ void cvt_kernel(const float4* __restrict__ x, ushort4* __restrict__ hb, int n4) {
    int i = blockIdx.x * 256 + threadIdx.x;
    if (i < n4) hb[i] = f4_to_bf4(x[i]);
}

// ---------------- weight packing into MFMA B-fragment layout ----------------
// Wc[192][64]: rows 0..63 = V_b0, 64..127 = V_b1, 128..191 = W_self.
// wfrag[conv][nt(4)][kidx(6)][lane(64)][j(8)]; n = nt*16+(lane&15),
// k = kidx*32+(lane>>4)*8+j.
__global__ void wpack_kernel(const float* __restrict__ lV, const float* __restrict__ lW,
                             const float* __restrict__ gV, const float* __restrict__ gW,
                             u16* __restrict__ wfrag) {
    int idx = blockIdx.x * 256 + threadIdx.x;   // 6*4*6*64 = 9216
    if (idx >= 6 * 4 * 6 * 64) return;
    int lane = idx & 63;
    int kidx = (idx >> 6) % 6;
    int nt   = (idx >> 6) / 6 % 4;
    int c    = idx / (64 * 6 * 4);      // conv 0..5
    int layer = c >> 1;
    bool isglobal = c & 1;
    const float* V = isglobal ? gV : lV;
    const float* W = isglobal ? gW : lW;
    int n = nt * 16 + (lane & 15);
    int kbase = kidx * 32 + (lane >> 4) * 8;
    u16 vals[8];
#pragma unroll
    for (int j = 0; j < 8; j++) {
        int r = kbase + j;      // 0..191
        float val;
        if (r < NBASES * DIM) {
            int b = r >> 6, d = r & 63;
            val = V[((layer * NBASES + b) * DIM + d) * DIM + n];
        } else {
            int d = r - NBASES * DIM;
            val = W[(layer * DIM + d) * DIM + n];
        }
        vals[j] = f2bf(val);
    }
    ushort4* o = (ushort4*)(wfrag + (size_t)idx * 8);
    o[0] = make_ushort4(vals[0], vals[1], vals[2], vals[3]);
    o[1] = make_ushort4(vals[4], vals[5], vals[6], vals[7]);
}

// ---------------- edge aggregation (wave per dst node, basis-space, bf16 h) ------
// h: bf16 [N,64]. t: bf16 [N,128] (u_b0 | u_b1; self-loop folded into gemm).
// Quarter-wave gathers: lanes q*16..+15 fetch edge j+4s+q's 128B row.
// which: 0 -> m1 (csr.y), 1 -> m2 (csr.z).
// list != nullptr: process list[idx] for idx < *nld (layer-2 local pruning).
__global__ __launch_bounds__(256) void agg_kernel(
    const ushort4* __restrict__ hb, const int* __restrict__ offs,
    const int4* __restrict__ csr, const float* __restrict__ Cc,
    int which, ushort4* __restrict__ t, int nNodes,
    const int* __restrict__ list, const int* __restrict__ nld) {
    int lane = threadIdx.x & 63;
    int idx = (blockIdx.x << 2) + (threadIdx.x >> 6);
    int n;
    if (list) {
        if (idx >= *nld) return;
        n = list[idx];
    } else {
        if (idx >= nNodes) return;
        n = idx;
    }
    int q  = lane >> 4;     // quarter 0..3
    int ql = lane & 15;     // lane within quarter
    float Ca0 = Cc[0], Cb0 = Cc[1], Ca1 = Cc[2], Cb1 = Cc[3], Ca2 = Cc[4], Cb2 = Cc[5];
    int beg = offs[n], end = offs[n + 1];
    float4 a0 = make_float4(0.f, 0.f, 0.f, 0.f);
    float4 a1 = make_float4(0.f, 0.f, 0.f, 0.f);
    for (int base = beg; base < end; base += 64) {
        int cnt = min(64, end - base);
        int p = 0; float m = 0.f;
        if (lane < cnt) {
            int4 meta = csr[base + lane];
            p = meta.x;
            m = __int_as_float(which ? meta.z : meta.y);
        }
        for (int j = 0; j < cnt; j += 32) {
            int pe[8]; float me[8]; ushort4 r[8];
#pragma unroll
            for (int s = 0; s < 8; s++) {
                int jj = j + (s << 2) + q;
                int ii = jj < cnt ? jj : 0;
                pe[s] = __shfl(p, ii, 64);
                float mm = __shfl(m, ii, 64);
                me[s] = jj < cnt ? mm : 0.f;
            }
#pragma unroll
            for (int s = 0; s < 8; s++)
                r[s] = hb[((pe[s] & 0xFFFFF) << 4) + ql];
#pragma unroll
            for (int s = 0; s < 8; s++) {
                float4 v = bf4_to_f4(r[s]);
                int et = pe[s] >> 20;
                float ca = et == 0 ? Ca0 : (et == 1 ? Ca1 : Ca2);
                float cb = et == 0 ? Cb0 : (et == 1 ? Cb1 : Cb2);
                float c0 = me[s] * ca, c1 = me[s] * cb;
                a0.x = fmaf(c0, v.x, a0.x); a0.y = fmaf(c0, v.y, a0.y);
                a0.z = fmaf(c0, v.z, a0.z); a0.w = fmaf(c0, v.w, a0.w);
                a1.x = fmaf(c1, v.x, a1.x); a1.y = fmaf(c1, v.y, a1.y);
                a1.z = fmaf(c1, v.z, a1.z); a1.w = fmaf(c1, v.w, a1.w);
            }
        }
    }
#pragma unroll
    for (int off = 16; off < 64; off <<= 1) {
        a0.x += __shfl_xor(a0.x, off, 64); a0.y += __shfl_xor(a0.y, off, 64);
        a0.z += __shfl_xor(a0.z, off, 64); a0.w += __shfl_xor(a0.w, off, 64);
        a1.x += __shfl_xor(a1.x, off, 64); a1.y += __shfl_xor(a1.y, off, 64);
        a1.z += __shfl_xor(a1.z, off, 64); a1.w += __shfl_xor(a1.w, off, 64);
    }
    ushort4 outv = f4_to_bf4(q == 0 ? a0 : a1);
    if (q < 2)
        t[(size_t)n * 32 + (q << 4) + ql] = outv;
}

// ---------------- MFMA GEMM: [rows,128(t)|64(h self)] @ wfrag[192,64] -----------
// 4 waves/block; wave owns 16 row-slots x 64 cols; K = 6 x mfma_f32_16x16x32_bf16
// (kidx 0..3 A from t, kidx 4..5 A from h). list: indirect rows (layer-2 local).
__global__ __launch_bounds__(256) void gemm_kernel(
    const u16* __restrict__ t, const u16* __restrict__ h,
    const u16* __restrict__ wfrag, const float* __restrict__ bias,
    u16* __restrict__ hout, float* __restrict__ subg, int subg_off, int act,
    const int* __restrict__ list, const int* __restrict__ nld) {
    int tid = threadIdx.x;
    int wave = tid >> 6, lane = tid & 63;
    int l16 = lane & 15, quad = lane >> 4;
    int nL = list ? *nld : 0;
    if (list && blockIdx.x * 64 >= nL) return;
    int slot0 = blockIdx.x * 64 + wave * 16;
    int myslot = slot0 + l16;
    int rowA = list ? list[min(myslot, nL - 1)] : myslot;
    const u16* trow = t + (size_t)rowA * 128;
    const u16* hrow = h + (size_t)rowA * 64;
    f32x4 acc0 = {0.f, 0.f, 0.f, 0.f};
    f32x4 acc1 = {0.f, 0.f, 0.f, 0.f};
    f32x4 acc2 = {0.f, 0.f, 0.f, 0.f};
    f32x4 acc3 = {0.f, 0.f, 0.f, 0.f};
#pragma unroll
    for (int kidx = 0; kidx < 6; kidx++) {
        bf16x8 a = (kidx < 4)
            ? *(const bf16x8*)(trow + kidx * 32 + quad * 8)
            : *(const bf16x8*)(hrow + (kidx - 4) * 32 + quad * 8);
        bf16x8 b0 = *(const bf16x8*)(wfrag + ((size_t)(0 * 6 + kidx) * 64 + lane) * 8);
        bf16x8 b1 = *(const bf16x8*)(wfrag + ((size_t)(1 * 6 + kidx) * 64 + lane) * 8);
        bf16x8 b2 = *(const bf16x8*)(wfrag + ((size_t)(2 * 6 + kidx) * 64 + lane) * 8);
        bf16x8 b3 = *(const bf16x8*)(wfrag + ((size_t)(3 * 6 + kidx) * 64 + lane) * 8);
        acc0 = __builtin_amdgcn_mfma_f32_16x16x32_bf16(a, b0, acc0, 0, 0, 0);
        acc1 = __builtin_amdgcn_mfma_f32_16x16x32_bf16(a, b1, acc1, 0, 0, 0);
        acc2 = __builtin_amdgcn_mfma_f32_16x16x32_bf16(a, b2, acc2, 0, 0, 0);
        acc3 = __builtin_amdgcn_mfma_f32_16x16x32_bf16(a, b3, acc3, 0, 0, 0);
    }
    float accs[4][4] = {
        {acc0[0], acc0[1], acc0[2], acc0[3]},
        {acc1[0], acc1[1], acc1[2], acc1[3]},
        {acc2[0], acc2[1], acc2[2], acc2[3]},
        {acc3[0], acc3[1], acc3[2], acc3[3]},
    };
#pragma unroll
    for (int nt = 0; nt < 4; nt++) {
        int col = nt * 16 + l16;
        float bcol = bias[col];
#pragma unroll
        for (int r = 0; r < 4; r++) {
            int cslot = slot0 + quad * 4 + r;
            if (list && cslot >= nL) continue;
            int row = list ? __shfl(rowA, quad * 4 + r, 64) : cslot;
            float xv = accs[nt][r] + bcol;
            float v = act ? (xv > 0.f ? xv : 0.01f * xv)
                          : (xv > 0.f ? xv : expm1f(xv));
            hout[(size_t)row * 64 + col] = f2bf(v);
            if (subg && row < BSUB)
                subg[(size_t)row * 192 + subg_off + col] = v;
        }
    }
}

// ---------------- MLP head: [4096,192] -> relu 128 -> sigmoid 1 ----------------
__global__ __launch_bounds__(256) void head_kernel(
    const float* __restrict__ subg, const float* __restrict__ w1,
    const float* __restrict__ b1, const float* __restrict__ w2,
    const float* __restrict__ b2, float* __restrict__ out) {
    __shared__ float srow[4][192];
    int lane = threadIdx.x & 63, wid = threadIdx.x >> 6;
    int row = blockIdx.x * 4 + wid;
    const float* sr = subg + (size_t)row * 192;
    srow[wid][lane] = sr[lane];
    srow[wid][64 + lane] = sr[64 + lane];
    srow[wid][128 + lane] = sr[128 + lane];
    __syncthreads();
    float acc1 = b1[lane], acc2 = b1[64 + lane];
    const float* w1a = w1 + lane * 192;
    const float* w1b = w1 + (64 + lane) * 192;
    for (int k = 0; k < 192; k++) {
        float s = srow[wid][k];
        acc1 = fmaf(s, w1a[k], acc1);
        acc2 = fmaf(s, w1b[k], acc2);
    }
    acc1 = fmaxf(acc1, 0.f);
    acc2 = fmaxf(acc2, 0.f);
    float part = acc1 * w2[lane] + acc2 * w2[64 + lane];
    for (int off = 32; off; off >>= 1) part += __shfl_down(part, off, 64);
    if (lane == 0) out[row] = 1.f / (1.f + expf(-(part + b2[0])));
}

extern "C" void kernel_launch(void* const* d_in, const int* in_sizes, int n_in,
                              void* d_out, int out_size, void* d_ws, size_t ws_size,
                              hipStream_t stream) {
    const float* x     = (const float*)d_in[0];
    const int*   src   = (const int*)d_in[1];
    const int*   dst   = (const int*)d_in[2];
    const int*   etype = (const int*)d_in[3];
    const float* mask  = (const float*)d_in[4];
    const float* mask2 = (const float*)d_in[5];
    const float* lV = (const float*)d_in[6];
    const float* lC = (const float*)d_in[7];
    const float* lW = (const float*)d_in[8];
    const float* lB = (const float*)d_in[9];
    const float* gV = (const float*)d_in[10];
    const float* gC = (const float*)d_in[11];
    const float* gW = (const float*)d_in[12];
    const float* gB = (const float*)d_in[13];
    const float* w1 = (const float*)d_in[14];
    const float* b1 = (const float*)d_in[15];
    const float* w2 = (const float*)d_in[16];
    const float* b2 = (const float*)d_in[17];
    float* out = (float*)d_out;

    // workspace carve-up
    char* ws = (char*)d_ws;
    size_t off = 0;
    auto alloc = [&](size_t bytes) {
        void* p = ws + off;
        off += (bytes + 255) & ~(size_t)255;
        return p;
    };
    ushort4* h    = (ushort4*)alloc((size_t)N_NODES * 64 * 2);     // bf16 [N,64]
    ushort4* t    = (ushort4*)alloc((size_t)N_NODES * 128 * 2);    // bf16 [N,128]
    int4*  csr    = (int4*)alloc((size_t)N_EDGES * 16);
    int*   offs   = (int*)alloc((size_t)(N_NODES + 1) * 4);
    int*   chist  = (int*)alloc(NCB * 4);
    int*   cbase  = (int*)alloc(NCB * 4);
    int*   ccur   = (int*)alloc(NCB * 4);
    int*   bsum   = (int*)alloc(512 * 4);
    int*   mark   = (int*)alloc((size_t)N_NODES * 4);
    int*   mpref  = (int*)alloc((size_t)N_NODES * 4);
    int*   mbsum  = (int*)alloc(512 * 4);
    int*   list   = (int*)alloc((size_t)N_NODES * 4);
    int*   nld    = (int*)alloc(256);
    u16*   wfrag  = (u16*)alloc((size_t)6 * 4 * 6 * 64 * 8 * 2);
    float* subg   = (float*)alloc((size_t)BSUB * 192 * 4);
    // tmp (coarse-sorted payload, 32 MB) aliases t: t is dead until agg.
    int4*  tmp    = (int4*)t;

    // ---- graph preprocessing (R17 sort pipeline) ----
    initmark_kernel<<<N_NODES / 256, 256, 0, stream>>>(mark, chist);
    chist_kernel<<<NCB, 256, 0, stream>>>(dst, chist);
    cscan_kernel<<<1, NCB, 0, stream>>>(chist, cbase, ccur, offs);
    cscatter_kernel<<<NCB, 256, 0, stream>>>(src, dst, etype, mask, mask2,
                                             ccur, tmp, mark);
    fscatter_kernel<<<NCB, 256, 0, stream>>>(tmp, cbase, chist, offs, csr);
    // frontier compaction for layer-2 local conv
    scan1_kernel<<<N_NODES / 256, 256, 0, stream>>>(mark, mpref, mbsum);
    scan2_kernel<<<1, 512, 0, stream>>>(mbsum);
    listfill_kernel<<<N_NODES / 256, 256, 0, stream>>>(mark, mpref, mbsum, list, nld);
    wpack_kernel<<<(6 * 4 * 6 * 64 + 255) / 256, 256, 0, stream>>>(lV, lW, gV, gW, wfrag);
    cvt_kernel<<<(N_NODES * 64 / 4) / 256, 256, 0, stream>>>((const float4*)x, h,
                                                             N_NODES * 64 / 4);

    const int convfrag = 4 * 6 * 64 * 8;   // u16 elements per conv
    for (int layer = 0; layer < 3; layer++) {
        // local conv (mask, elu); layer 2: frontier-pruned
        const int* ll  = (layer == 2) ? list : nullptr;
        agg_kernel<<<N_NODES / 4, 256, 0, stream>>>(h, offs, csr,
            lC + layer * NREL * NBASES, 0, t, N_NODES, ll, nld);
        gemm_kernel<<<N_NODES / 64, 256, 0, stream>>>(
            (const u16*)t, (const u16*)h,
            wfrag + (size_t)(layer * 2 + 0) * convfrag, lB + layer * 64,
            (u16*)h, nullptr, 0, 0, ll, nld);
        // global conv (mask2, leaky_relu); layer 2: only BSUB rows
        int nG = (layer == 2) ? BSUB : N_NODES;
        agg_kernel<<<(nG + 3) / 4, 256, 0, stream>>>(h, offs, csr,
            gC + layer * NREL * NBASES, 1, t, nG, nullptr, nld);
        gemm_kernel<<<nG / 64, 256, 0, stream>>>(
            (const u16*)t, (const u16*)h,
            wfrag + (size_t)(layer * 2 + 1) * convfrag, gB + layer * 64,
            (u16*)h, subg, layer * 64, 1, nullptr, nld);
    }
    head_kernel<<<BSUB / 4, 256, 0, stream>>>(subg, w1, b1, w2, b2, out);
}

// Round 7
// 650.071 us; speedup vs baseline: 1.1444x; 1.0406x over previous
//
#include <hip/hip_runtime.h>
#include <math.h>

#define N_NODES 131072
#define N_EDGES 2097152
#define DIM     64
#define BSUB    4096
#define NREL    3
#define NBASES  2
#define NCB     256     // coarse buckets (dst >> 9)
#define CBSZ    8192    // edges per chist/cscatter block (256 blocks exactly)

typedef unsigned short u16;
typedef __attribute__((ext_vector_type(8))) short bf16x8;   // MFMA A/B frag (4 VGPRs)
typedef __attribute__((ext_vector_type(4))) float f32x4;    // MFMA C/D frag

__device__ __forceinline__ float bf2f(u16 x) {
    return __uint_as_float(((unsigned)x) << 16);
}
__device__ __forceinline__ u16 f2bf(float f) {
    unsigned u = __float_as_uint(f);
    unsigned r = (u + 0x7FFFu + ((u >> 16) & 1u)) >> 16;   // RNE
    return (u16)r;
}
__device__ __forceinline__ float4 bf4_to_f4(ushort4 u) {
    return make_float4(bf2f(u.x), bf2f(u.y), bf2f(u.z), bf2f(u.w));
}
__device__ __forceinline__ ushort4 f4_to_bf4(float4 v) {
    ushort4 o; o.x = f2bf(v.x); o.y = f2bf(v.y); o.z = f2bf(v.z); o.w = f2bf(v.w);
    return o;
}

// ================= R17: MSD bucket sort replaces atomic CSR build ==============
// R2-R5 established: global returning atomics are capped ~24 G/s chip-wide,
// invariant to line padding (R14), per-wave ILP (R15), and atomic scope (R16)
// — they execute memory-side (32 B/atomic WRITE traffic signature). This sort
// uses only LDS atomics per edge + 65K global atomics per pass (negligible).

// ---------------- init: mark centers + zero coarse histogram ----------------
__global__ void initmark_kernel(int* __restrict__ mark, int* __restrict__ chist) {
    int i = blockIdx.x * 256 + threadIdx.x;
    if (i < N_NODES) mark[i] = (i < BSUB) ? 1 : 0;
    if (i < NCB) chist[i] = 0;
}

// ---------------- pass A: coarse histogram (dst >> 9) ----------------
__global__ __launch_bounds__(256) void chist_kernel(const int* __restrict__ dst,
                                                    int* __restrict__ chist) {
    __shared__ int lh[NCB];
    int tid = threadIdx.x;
    lh[tid] = 0;
    __syncthreads();
    int base = blockIdx.x * CBSZ + tid;
#pragma unroll
    for (int j = 0; j < CBSZ / 256; j++)
        atomicAdd(&lh[dst[base + j * 256] >> 9], 1);
    __syncthreads();
    atomicAdd(&chist[tid], lh[tid]);     // non-returning, 256/block
}

// ---------------- coarse scan: chist -> cbase (excl) + ccur copy ----------------
__global__ void cscan_kernel(const int* __restrict__ chist, int* __restrict__ cbase,
                             int* __restrict__ ccur, int* __restrict__ offs) {
    __shared__ int s[NCB];
    int tid = threadIdx.x;
    int v = chist[tid];
    s[tid] = v;
    __syncthreads();
    int val = v;
    for (int off = 1; off < NCB; off <<= 1) {
        int tmp = (tid >= off) ? s[tid - off] : 0;
        __syncthreads();
        val += tmp;
        s[tid] = val;
        __syncthreads();
    }
    cbase[tid] = val - v;
    ccur[tid] = val - v;
    if (tid == 0) offs[N_NODES] = N_EDGES;
}

// ---------------- pass B: coarse scatter (full payload) + frontier mark --------
// Each block: LDS-hist its 8192 edges, claim per-bin runs (256 returning
// global atomics/block = 65K total), scatter {src|et, m1, m2, dst} into tmp.
__global__ __launch_bounds__(256) void cscatter_kernel(
    const int* __restrict__ src, const int* __restrict__ dst,
    const int* __restrict__ et, const float* __restrict__ m1,
    const float* __restrict__ m2, int* __restrict__ ccur,
    int4* __restrict__ tmp, int* __restrict__ mark) {
    __shared__ int lh[NCB];
    __shared__ int lbase[NCB];
    int tid = threadIdx.x;
    lh[tid] = 0;
    __syncthreads();
    int e0 = blockIdx.x * CBSZ;
#pragma unroll
    for (int j = 0; j < CBSZ / 256; j++)
        atomicAdd(&lh[dst[e0 + tid + j * 256] >> 9], 1);
    __syncthreads();
    int c = lh[tid];
    lbase[tid] = c ? atomicAdd(&ccur[tid], c) : 0;
    lh[tid] = 0;                 // reuse as local cursor
    __syncthreads();
#pragma unroll
    for (int j = 0; j < CBSZ / 256; j++) {
        int e = e0 + tid + j * 256;
        int d = dst[e];
        int s = src[e];
        int b = d >> 9;
        int r = atomicAdd(&lh[b], 1);            // LDS returning
        int4 v;
        v.x = s | (et[e] << 20);
        v.y = __float_as_int(m1[e]);
        v.z = __float_as_int(m2[e]);
        v.w = d;
        tmp[lbase[b] + r] = v;
        if (d < BSUB) mark[s] = 1;               // benign race: all write 1
    }
}

// ---------------- pass C: fine scatter within coarse bucket + offs write -------
// One WG per bucket (512 nodes, ~8192 edges, 128 KB csr region -> XCD-L2-local).
// LDS 512-bin hist + scan -> offs[] directly; then scatter csr by LDS ranks.
__global__ __launch_bounds__(256) void fscatter_kernel(
    const int4* __restrict__ tmp, const int* __restrict__ cbase,
    const int* __restrict__ chist, int* __restrict__ offs,
    int4* __restrict__ csr) {
    __shared__ int lh[512];
    __shared__ int lpre[512];
    __shared__ int s2[256];
    int b = blockIdx.x;
    int tid = threadIdx.x;
    int base = cbase[b], cnt = chist[b];
    lh[tid] = 0; lh[tid + 256] = 0;
    __syncthreads();
    for (int i = tid; i < cnt; i += 256)
        atomicAdd(&lh[tmp[base + i].w & 511], 1);
    __syncthreads();
    // exclusive scan of 512 bins (pair + 256-scan + expand)
    int a0 = lh[2 * tid], a1 = lh[2 * tid + 1];
    s2[tid] = a0 + a1;
    __syncthreads();
    int val = s2[tid];
    for (int off = 1; off < 256; off <<= 1) {
        int t = (tid >= off) ? s2[tid - off] : 0;
        __syncthreads();
        val += t;
        s2[tid] = val;
        __syncthreads();
    }
    int ex = val - (a0 + a1);
    lpre[2 * tid] = ex;
    lpre[2 * tid + 1] = ex + a0;
    // offs for this bucket's 512 nodes
    offs[b * 512 + 2 * tid]     = base + ex;
    offs[b * 512 + 2 * tid + 1] = base + ex + a0;
    lh[tid] = 0; lh[tid + 256] = 0;    // reuse as cursors
    __syncthreads();
    for (int i = tid; i < cnt; i += 256) {
        int4 v = tmp[base + i];
        int k = v.w & 511;
        int r = atomicAdd(&lh[k], 1);            // LDS returning
        csr[base + lpre[k] + r] = v;             // .w carries dst (agg ignores)
    }
}

// block-level exclusive scan of 256 ints; block total -> bsum (mark compaction)
__global__ void scan1_kernel(const int* __restrict__ cnt, int* __restrict__ scanned,
                             int* __restrict__ bsum) {
    __shared__ int s[256];
    int tid = threadIdx.x;
    int i = blockIdx.x * 256 + tid;
    int v = cnt[i];
    s[tid] = v;
    __syncthreads();
    int val = v;
    for (int off = 1; off < 256; off <<= 1) {
        int tmp = (tid >= off) ? s[tid - off] : 0;
        __syncthreads();
        val += tmp;
        s[tid] = val;
        __syncthreads();
    }
    scanned[i] = val - v;                 // exclusive
    if (tid == 255) bsum[blockIdx.x] = val;
}

// exclusive scan of 512 block sums, in place
__global__ void scan2_kernel(int* __restrict__ bsum) {
    __shared__ int s[512];
    int tid = threadIdx.x;
    int v = bsum[tid];
    s[tid] = v;
    __syncthreads();
    int val = v;
    for (int off = 1; off < 512; off <<= 1) {
        int tmp = (tid >= off) ? s[tid - off] : 0;
        __syncthreads();
        val += tmp;
        s[tid] = val;
        __syncthreads();
    }
    bsum[tid] = val - v;
}

// compact marked nodes -> list[], write count to nld
__global__ void listfill_kernel(const int* __restrict__ mark, const int* __restrict__ mpref,
                                const int* __restrict__ mbsum, int* __restrict__ list,
                                int* __restrict__ nld) {
    int i = blockIdx.x * 256 + threadIdx.x;
    int pos = mpref[i] + mbsum[blockIdx.x];
    if (mark[i]) list[pos] = i;
    if (i == N_NODES - 1) *nld = pos + mark[i];
}

// ---------------- x -> bf16 convert ----------------
__global__ void cvt_kernel(const float4* __restrict__ x, ushort4* __restrict__ hb, int n4) {
    int i = blockIdx.x * 256 + threadIdx.x;
    if (i < n4) hb[i] = f4_to_bf4(x[i]);
}

// ---------------- weight packing into MFMA B-fragment layout ----------------
// Wc[192][64]: rows 0..63 = V_b0, 64..127 = V_b1, 128..191 = W_self.
// wfrag[conv][nt(4)][kidx(6)][lane(64)][j(8)]; n = nt*16+(lane&15),
// k = kidx*32+(lane>>4)*8+j.
__global__ void wpack_kernel(const float* __restrict__ lV, const float* __restrict__ lW,
                             const float* __restrict__ gV, const float* __restrict__ gW,
                             u16* __restrict__ wfrag) {
    int idx = blockIdx.x * 256 + threadIdx.x;   // 6*4*6*64 = 9216
    if (idx >= 6 * 4 * 6 * 64) return;
    int lane = idx & 63;
    int kidx = (idx >> 6) % 6;
    int nt   = (idx >> 6) / 6 % 4;
    int c    = idx / (64 * 6 * 4);      // conv 0..5
    int layer = c >> 1;
    bool isglobal = c & 1;
    const float* V = isglobal ? gV : lV;
    const float* W = isglobal ? gW : lW;
    int n = nt * 16 + (lane & 15);
    int kbase = kidx * 32 + (lane >> 4) * 8;
    u16 vals[8];
#pragma unroll
    for (int j = 0; j < 8; j++) {
        int r = kbase + j;      // 0..191
        float val;
        if (r < NBASES * DIM) {
            int b = r >> 6, d = r & 63;
            val = V[((layer * NBASES + b) * DIM + d) * DIM + n];
        } else {
            int d = r - NBASES * DIM;
            val = W[(layer * DIM + d) * DIM + n];
        }
        vals[j] = f2bf(val);
    }
    ushort4* o = (ushort4*)(wfrag + (size_t)idx * 8);
    o[0] = make_ushort4(vals[0], vals[1], vals[2], vals[3]);
    o[1] = make_ushort4(vals[4], vals[5], vals[6], vals[7]);
}

// ---------------- edge aggregation (wave per dst node, basis-space, bf16 h) ------
// R18: LDS meta-stage. R6 counters: VALUBusy 85%, MfmaUtil 0, HBM 28% ->
// VALU-instruction-bound. Old inner loop spent ~25 VALU/edge-slot, only 8 of
// them payload FMAs, and recomputed the et-decode/coeff-select per-edge x16
// lanes. Now: the chunk's meta is decoded ONCE per edge by its owning lane
// (et-select + m*C mults), packed {src<<4, c0, c1} into a 16B LDS slot
// (zero-filled beyond cnt -> no bounds logic in inner loop). Inner loop per
// edge-slot: 1 ds_read_b128 (quarter-broadcast, conflict-free) + gather +
// 4 cvt shifts + 8 fma ~= 14 VALU.
__global__ __launch_bounds__(256) void agg_kernel(
    const ushort4* __restrict__ hb, const int* __restrict__ offs,
    const int4* __restrict__ csr, const float* __restrict__ Cc,
    int which, ushort4* __restrict__ t, int nNodes,
    const int* __restrict__ list, const int* __restrict__ nld) {
    __shared__ int4 lmeta[4][64];
    int lane = threadIdx.x & 63;
    int wid  = threadIdx.x >> 6;
    int idx = (blockIdx.x << 2) + wid;
    int n;
    if (list) {
        if (idx >= *nld) return;
        n = list[idx];
    } else {
        if (idx >= nNodes) return;
        n = idx;
    }
    int q  = lane >> 4;     // quarter 0..3
    int ql = lane & 15;     // lane within quarter
    float Ca0 = Cc[0], Cb0 = Cc[1], Ca1 = Cc[2], Cb1 = Cc[3], Ca2 = Cc[4], Cb2 = Cc[5];
    int beg = offs[n], end = offs[n + 1];
    float4 a0 = make_float4(0.f, 0.f, 0.f, 0.f);
    float4 a1 = make_float4(0.f, 0.f, 0.f, 0.f);
    for (int base = beg; base < end; base += 64) {
        int cnt = min(64, end - base);
        int pp = 0; float c0 = 0.f, c1 = 0.f;
        if (lane < cnt) {
            int4 meta = csr[base + lane];
            int et = ((unsigned)meta.x) >> 20;
            float m = __int_as_float(which ? meta.z : meta.y);
            float ca = et == 0 ? Ca0 : (et == 1 ? Ca1 : Ca2);
            float cb = et == 0 ? Cb0 : (et == 1 ? Cb1 : Cb2);
            pp = (meta.x & 0xFFFFF) << 4;        // pre-scaled hb row base
            c0 = m * ca;
            c1 = m * cb;
        }
        lmeta[wid][lane] = make_int4(pp, __float_as_int(c0), __float_as_int(c1), 0);
        // wave-local LDS: compiler inserts lgkmcnt ordering; no cross-wave use
        for (int j = 0; j < cnt; j += 32) {
#pragma unroll
            for (int s = 0; s < 8; s++) {
                int4 md = lmeta[wid][j + (s << 2) + q];   // broadcast per quarter
                ushort4 rv = hb[md.x + ql];
                float4 v = bf4_to_f4(rv);
                float e0 = __int_as_float(md.y);
                float e1 = __int_as_float(md.z);
                a0.x = fmaf(e0, v.x, a0.x); a0.y = fmaf(e0, v.y, a0.y);
                a0.z = fmaf(e0, v.z, a0.z); a0.w = fmaf(e0, v.w, a0.w);
                a1.x = fmaf(e1, v.x, a1.x); a1.y = fmaf(e1, v.y, a1.y);
                a1.z = fmaf(e1, v.z, a1.z); a1.w = fmaf(e1, v.w, a1.w);
            }
        }
    }
#pragma unroll
    for (int off = 16; off < 64; off <<= 1) {
        a0.x += __shfl_xor(a0.x, off, 64); a0.y += __shfl_xor(a0.y, off, 64);
        a0.z += __shfl_xor(a0.z, off, 64); a0.w += __shfl_xor(a0.w, off, 64);
        a1.x += __shfl_xor(a1.x, off, 64); a1.y += __shfl_xor(a1.y, off, 64);
        a1.z += __shfl_xor(a1.z, off, 64); a1.w += __shfl_xor(a1.w, off, 64);
    }
    ushort4 outv = f4_to_bf4(q == 0 ? a0 : a1);
    if (q < 2)
        t[(size_t)n * 32 + (q << 4) + ql] = outv;
}

// ---------------- MFMA GEMM: [rows,128(t)|64(h self)] @ wfrag[192,64] -----------
// 4 waves/block; wave owns 16 row-slots x 64 cols; K = 6 x mfma_f32_16x16x32_bf16
// (kidx 0..3 A from t, kidx 4..5 A from h). list: indirect rows (layer-2 local).
__global__ __launch_bounds__(256) void gemm_kernel(
    const u16* __restrict__ t, const u16* __restrict__ h,
    const u16* __restrict__ wfrag, const float* __restrict__ bias,
    u16* __restrict__ hout, float* __restrict__ subg, int subg_off, int act,
    const int* __restrict__ list, const int* __restrict__ nld) {
    int tid = threadIdx.x;
    int wave = tid >> 6, lane = tid & 63;
    int l16 = lane & 15, quad = lane >> 4;
    int nL = list ? *nld : 0;
    if (list && blockIdx.x * 64 >= nL) return;
    int slot0 = blockIdx.x * 64 + wave * 16;
    int myslot = slot0 + l16;
    int rowA = list ? list[min(myslot, nL - 1)] : myslot;
    const u16* trow = t + (size_t)rowA * 128;
    const u16* hrow = h + (size_t)rowA * 64;
    f32x4 acc0 = {0.f, 0.f, 0.f, 0.f};
    f32x4 acc1 = {0.f, 0.f, 0.f, 0.f};
    f32x4 acc2 = {0.f, 0.f, 0.f, 0.f};
    f32x4 acc3 = {0.f, 0.f, 0.f, 0.f};
#pragma unroll
    for (int kidx = 0; kidx < 6; kidx++) {
        bf16x8 a = (kidx < 4)
            ? *(const bf16x8*)(trow + kidx * 32 + quad * 8)
            : *(const bf16x8*)(hrow + (kidx - 4) * 32 + quad * 8);
        bf16x8 b0 = *(const bf16x8*)(wfrag + ((size_t)(0 * 6 + kidx) * 64 + lane) * 8);
        bf16x8 b1 = *(const bf16x8*)(wfrag + ((size_t)(1 * 6 + kidx) * 64 + lane) * 8);
        bf16x8 b2 = *(const bf16x8*)(wfrag + ((size_t)(2 * 6 + kidx) * 64 + lane) * 8);
        bf16x8 b3 = *(const bf16x8*)(wfrag + ((size_t)(3 * 6 + kidx) * 64 + lane) * 8);
        acc0 = __builtin_amdgcn_mfma_f32_16x16x32_bf16(a, b0, acc0, 0, 0, 0);
        acc1 = __builtin_amdgcn_mfma_f32_16x16x32_bf16(a, b1, acc1, 0, 0, 0);
        acc2 = __builtin_amdgcn_mfma_f32_16x16x32_bf16(a, b2, acc2, 0, 0, 0);
        acc3 = __builtin_amdgcn_mfma_f32_16x16x32_bf16(a, b3, acc3, 0, 0, 0);
    }
    float accs[4][4] = {
        {acc0[0], acc0[1], acc0[2], acc0[3]},
        {acc1[0], acc1[1], acc1[2], acc1[3]},
        {acc2[0], acc2[1], acc2[2], acc2[3]},
        {acc3[0], acc3[1], acc3[2], acc3[3]},
    };
#pragma unroll
    for (int nt = 0; nt < 4; nt++) {
        int col = nt * 16 + l16;
        float bcol = bias[col];
#pragma unroll
        for (int r = 0; r < 4; r++) {
            int cslot = slot0 + quad * 4 + r;
            if (list && cslot >= nL) continue;
            int row = list ? __shfl(rowA, quad * 4 + r, 64) : cslot;
            float xv = accs[nt][r] + bcol;
            float v = act ? (xv > 0.f ? xv : 0.01f * xv)
                          : (xv > 0.f ? xv : expm1f(xv));
            hout[(size_t)row * 64 + col] = f2bf(v);
            if (subg && row < BSUB)
                subg[(size_t)row * 192 + subg_off + col] = v;
        }
    }
}

// ---------------- MLP head: [4096,192] -> relu 128 -> sigmoid 1 ----------------
__global__ __launch_bounds__(256) void head_kernel(
    const float* __restrict__ subg, const float* __restrict__ w1,
    const float* __restrict__ b1, const float* __restrict__ w2,
    const float* __restrict__ b2, float* __restrict__ out) {
    __shared__ float srow[4][192];
    int lane = threadIdx.x & 63, wid = threadIdx.x >> 6;
    int row = blockIdx.x * 4 + wid;
    const float* sr = subg + (size_t)row * 192;
    srow[wid][lane] = sr[lane];
    srow[wid][64 + lane] = sr[64 + lane];
    srow[wid][128 + lane] = sr[128 + lane];
    __syncthreads();
    float acc1 = b1[lane], acc2 = b1[64 + lane];
    const float* w1a = w1 + lane * 192;
    const float* w1b = w1 + (64 + lane) * 192;
    for (int k = 0; k < 192; k++) {
        float s = srow[wid][k];
        acc1 = fmaf(s, w1a[k], acc1);
        acc2 = fmaf(s, w1b[k], acc2);
    }
    acc1 = fmaxf(acc1, 0.f);
    acc2 = fmaxf(acc2, 0.f);
    float part = acc1 * w2[lane] + acc2 * w2[64 + lane];
    for (int off = 32; off; off >>= 1) part += __shfl_down(part, off, 64);
    if (lane == 0) out[row] = 1.f / (1.f + expf(-(part + b2[0])));
}

extern "C" void kernel_launch(void* const* d_in, const int* in_sizes, int n_in,
                              void* d_out, int out_size, void* d_ws, size_t ws_size,
                              hipStream_t stream) {
    const float* x     = (const float*)d_in[0];
    const int*   src   = (const int*)d_in[1];
    const int*   dst   = (const int*)d_in[2];
    const int*   etype = (const int*)d_in[3];
    const float* mask  = (const float*)d_in[4];
    const float* mask2 = (const float*)d_in[5];
    const float* lV = (const float*)d_in[6];
    const float* lC = (const float*)d_in[7];
    const float* lW = (const float*)d_in[8];
    const float* lB = (const float*)d_in[9];
    const float* gV = (const float*)d_in[10];
    const float* gC = (const float*)d_in[11];
    const float* gW = (const float*)d_in[12];
    const float* gB = (const float*)d_in[13];
    const float* w1 = (const float*)d_in[14];
    const float* b1 = (const float*)d_in[15];
    const float* w2 = (const float*)d_in[16];
    const float* b2 = (const float*)d_in[17];
    float* out = (float*)d_out;

    // workspace carve-up
    char* ws = (char*)d_ws;
    size_t off = 0;
    auto alloc = [&](size_t bytes) {
        void* p = ws + off;
        off += (bytes + 255) & ~(size_t)255;
        return p;
    };
    ushort4* h    = (ushort4*)alloc((size_t)N_NODES * 64 * 2);     // bf16 [N,64]
    ushort4* t    = (ushort4*)alloc((size_t)N_NODES * 128 * 2);    // bf16 [N,128]
    int4*  csr    = (int4*)alloc((size_t)N_EDGES * 16);
    int*   offs   = (int*)alloc((size_t)(N_NODES + 1) * 4);
    int*   chist  = (int*)alloc(NCB * 4);
    int*   cbase  = (int*)alloc(NCB * 4);
    int*   ccur   = (int*)alloc(NCB * 4);
    int*   bsum   = (int*)alloc(512 * 4);
    int*   mark   = (int*)alloc((size_t)N_NODES * 4);
    int*   mpref  = (int*)alloc((size_t)N_NODES * 4);
    int*   mbsum  = (int*)alloc(512 * 4);
    int*   list   = (int*)alloc((size_t)N_NODES * 4);
    int*   nld    = (int*)alloc(256);
    u16*   wfrag  = (u16*)alloc((size_t)6 * 4 * 6 * 64 * 8 * 2);
    float* subg   = (float*)alloc((size_t)BSUB * 192 * 4);
    // tmp (coarse-sorted payload, 32 MB) aliases t: t is dead until agg.
    int4*  tmp    = (int4*)t;

    // ---- graph preprocessing (R17 sort pipeline) ----
    initmark_kernel<<<N_NODES / 256, 256, 0, stream>>>(mark, chist);
    chist_kernel<<<NCB, 256, 0, stream>>>(dst, chist);
    cscan_kernel<<<1, NCB, 0, stream>>>(chist, cbase, ccur, offs);
    cscatter_kernel<<<NCB, 256, 0, stream>>>(src, dst, etype, mask, mask2,
                                             ccur, tmp, mark);
    fscatter_kernel<<<NCB, 256, 0, stream>>>(tmp, cbase, chist, offs, csr);
    // frontier compaction for layer-2 local conv
    scan1_kernel<<<N_NODES / 256, 256, 0, stream>>>(mark, mpref, mbsum);
    scan2_kernel<<<1, 512, 0, stream>>>(mbsum);
    listfill_kernel<<<N_NODES / 256, 256, 0, stream>>>(mark, mpref, mbsum, list, nld);
    wpack_kernel<<<(6 * 4 * 6 * 64 + 255) / 256, 256, 0, stream>>>(lV, lW, gV, gW, wfrag);
    cvt_kernel<<<(N_NODES * 64 / 4) / 256, 256, 0, stream>>>((const float4*)x, h,
                                                             N_NODES * 64 / 4);

    const int convfrag = 4 * 6 * 64 * 8;   // u16 elements per conv
    for (int layer = 0; layer < 3; layer++) {
        // local conv (mask, elu); layer 2: frontier-pruned
        const int* ll  = (layer == 2) ? list : nullptr;
        agg_kernel<<<N_NODES / 4, 256, 0, stream>>>(h, offs, csr,
            lC + layer * NREL * NBASES, 0, t, N_NODES, ll, nld);
        gemm_kernel<<<N_NODES / 64, 256, 0, stream>>>(
            (const u16*)t, (const u16*)h,
            wfrag + (size_t)(layer * 2 + 0) * convfrag, lB + layer * 64,
            (u16*)h, nullptr, 0, 0, ll, nld);
        // global conv (mask2, leaky_relu); layer 2: only BSUB rows
        int nG = (layer == 2) ? BSUB : N_NODES;
        agg_kernel<<<(nG + 3) / 4, 256, 0, stream>>>(h, offs, csr,
            gC + layer * NREL * NBASES, 1, t, nG, nullptr, nld);
        gemm_kernel<<<nG / 64, 256, 0, stream>>>(
            (const u16*)t, (const u16*)h,
            wfrag + (size_t)(layer * 2 + 1) * convfrag, gB + layer * 64,
            (u16*)h, subg, layer * 64, 1, nullptr, nld);
    }
    head_kernel<<<BSUB / 4, 256, 0, stream>>>(subg, w1, b1, w2, b2, out);
}